// Round 7
// baseline (324.096 us; speedup 1.0000x reference)
//
#include <hip/hip_runtime.h>

#define N_NODES 100000
#define N_EDGES 3200000
#define F_IN 128
#define HID 16

#define SHIFT 8
#define NPB 256                                 // nodes per bucket
#define NB 391                                  // ceil(N/256)
#define CHUNK 3072
#define NCHUNK ((N_EDGES + CHUNK - 1) / CHUNK)  // 1042
#define MAXBE 9216                              // region cap per bucket (mean 8192, +11 sigma)
#define HALF 4608                               // region cap per half-bucket (mean 4096, +8 sigma)
#define CPAD 16

// ---------------- partition into fixed bucket regions, LDS-staged coalesced writes ----------------
__global__ __launch_bounds__(256) void k_part(const int* __restrict__ src,
                                              const int* __restrict__ dst,
                                              int* __restrict__ cursor,
                                              unsigned* __restrict__ ebuf, int E) {
    __shared__ int lcnt[512];
    __shared__ int sc[512];
    __shared__ int lcur[512];
    __shared__ int dlt[512];
    __shared__ unsigned sbuf[CHUNK];         // 12 KB
    __shared__ unsigned short sbkt[CHUNK];   // 6 KB
    int t = threadIdx.x;
    lcnt[t] = 0;
    lcnt[t + 256] = 0;
    __syncthreads();
    int e0 = blockIdx.x * CHUNK;
    int ne = min(CHUNK, E - e0);
    for (int e = t; e < ne; e += 256) atomicAdd(&lcnt[dst[e0 + e] >> SHIFT], 1);
    __syncthreads();
    sc[t] = lcnt[t];
    sc[t + 256] = lcnt[t + 256];
    __syncthreads();
#pragma unroll
    for (int o = 1; o < 256; o <<= 1) {
        int xv = (t >= o) ? sc[t - o] : 0;
        int yv = (t >= o) ? sc[256 + t - o] : 0;
        __syncthreads();
        sc[t] += xv;
        sc[256 + t] += yv;
        __syncthreads();
    }
    int tot1 = sc[255];
    __syncthreads();
    sc[256 + t] += tot1;
    __syncthreads();
    {
        int b1 = t, b2 = t + 256;
        int c1 = lcnt[b1], c2 = lcnt[b2];
        int o1 = sc[b1] - c1, o2 = sc[b2] - c2;
        lcur[b1] = o1;
        lcur[b2] = o2;
        if (b1 < NB && c1) dlt[b1] = b1 * MAXBE + atomicAdd(&cursor[b1 * CPAD], c1) - o1;
        if (b2 < NB && c2) dlt[b2] = b2 * MAXBE + atomicAdd(&cursor[b2 * CPAD], c2) - o2;
    }
    __syncthreads();
    for (int e = t; e < ne; e += 256) {
        int d = dst[e0 + e];
        int b = d >> SHIFT;
        int p = atomicAdd(&lcur[b], 1);
        sbuf[p] = ((unsigned)src[e0 + e] << SHIFT) | (unsigned)(d & (NPB - 1));
        sbkt[p] = (unsigned short)b;
    }
    __syncthreads();
    for (int k = t; k < ne; k += 256) ebuf[k + dlt[sbkt[k]]] = sbuf[k];
}

// ---------------- half-bucket counting-sort -> exact CSR (+dinv) + fused GEMM1 ----------------
// 2 blocks per bucket; block handles 128 nodes. Also computes g = (x@W1)*dinv for its nodes.
__global__ __launch_bounds__(256) void k_sort2(const unsigned* __restrict__ ebuf,
                                               const int* __restrict__ cursor,
                                               const float* __restrict__ x,
                                               const float* __restrict__ W1,
                                               int* __restrict__ ebuf2,
                                               int2* __restrict__ offse,
                                               float* __restrict__ dinv,
                                               float* __restrict__ g, int N) {
    __shared__ int hist[128];
    __shared__ int sc2[128];
    __shared__ int cur[128];
    __shared__ int dg[128];
    __shared__ int sbufS[HALF];       // 18 KB
    __shared__ float w1s[F_IN * HID]; // 8 KB
    int t = threadIdx.x;
    int b = blockIdx.x >> 1, h = blockIdx.x & 1;
    for (int idx = t; idx < F_IN * HID; idx += 256) w1s[idx] = W1[idx];
    if (t < 128) hist[t] = 0;
    __syncthreads();
    int cnt = cursor[b * CPAD];
    int base_r = b * MAXBE;
    for (int e = t; e < cnt; e += 256) {
        unsigned u = ebuf[base_r + e];
        unsigned dl = u & 255u;
        if ((int)(dl >> 7) == h) atomicAdd(&hist[dl & 127], 1);
    }
    __syncthreads();
    int v = (t < 128) ? hist[t] : 0;
    if (t < 128) sc2[t] = v;
    __syncthreads();
    for (int o = 1; o < 128; o <<= 1) {
        int xv = (t < 128 && t >= o) ? sc2[t - o] : 0;
        __syncthreads();
        if (t < 128) sc2[t] += xv;
        __syncthreads();
    }
    int base_w = (2 * b + h) * HALF;
    if (t < 128) {
        int ex = sc2[t] - v;
        cur[t] = ex;
        dg[t] = v;
        int i = b * NPB + h * 128 + t;
        if (i < N) {
            offse[i] = make_int2(base_w + ex, base_w + ex + v);
            dinv[i] = rsqrtf((float)(v + 1));  // +1 self-loop
        }
    }
    __syncthreads();
    for (int e = t; e < cnt; e += 256) {
        unsigned u = ebuf[base_r + e];
        unsigned dl = u & 255u;
        if ((int)(dl >> 7) == h) {
            int p = atomicAdd(&cur[dl & 127], 1);
            sbufS[p] = (int)(u >> SHIFT);
        }
    }
    __syncthreads();
    int m = sc2[127];
    for (int k = t; k < m; k += 256) ebuf2[base_w + k] = sbufS[k];  // coalesced
    // ---- fused GEMM1: g = (x @ W1) * dinv for this block's 128 nodes (2 lanes/row) ----
    int r = t >> 1, hf = t & 1;
    int i = b * NPB + h * 128 + r;
    float acc[HID];
#pragma unroll
    for (int n = 0; n < HID; n++) acc[n] = 0.f;
    if (i < N) {
        const float4* xr = (const float4*)(x + (size_t)i * F_IN + hf * (F_IN / 2));
#pragma unroll 4
        for (int k4 = 0; k4 < F_IN / 8; k4++) {
            float4 xv = xr[k4];
            int k = hf * (F_IN / 2) + k4 * 4;
#pragma unroll
            for (int n = 0; n < HID; n++) {
                acc[n] += xv.x * w1s[(k + 0) * HID + n] + xv.y * w1s[(k + 1) * HID + n] +
                          xv.z * w1s[(k + 2) * HID + n] + xv.w * w1s[(k + 3) * HID + n];
            }
        }
    }
#pragma unroll
    for (int n = 0; n < HID; n++) acc[n] += __shfl_xor(acc[n], 1);
    if (hf == 0 && i < N) {
        float dv = rsqrtf((float)(dg[r] + 1));
        float4* go = (float4*)(g + (size_t)i * HID);
#pragma unroll
        for (int n4 = 0; n4 < 4; n4++) {
            float4 o;
            o.x = acc[n4 * 4 + 0] * dv;
            o.y = acc[n4 * 4 + 1] * dv;
            o.z = acc[n4 * 4 + 2] * dv;
            o.w = acc[n4 * 4 + 3] * dv;
            go[n4] = o;
        }
    }
}

// ---------------- gather conv1 + fused GEMM2: g2 = (relu(dinv*(sum+self)+b1) @ W2) * dinv ----------------
__global__ __launch_bounds__(256) void k_gather1(const float* __restrict__ g,
                                                 const int2* __restrict__ offse,
                                                 const int* __restrict__ ebuf2,
                                                 const float* __restrict__ dinv,
                                                 const float* __restrict__ b1,
                                                 const float* __restrict__ W2,
                                                 float* __restrict__ g2, int N) {
    __shared__ float w2s[HID * HID];
    w2s[threadIdx.x] = W2[threadIdx.x];
    __syncthreads();
    int i = (blockIdx.x * 256 + threadIdx.x) >> 6;
    int lane = threadIdx.x & 63;
    if (i >= N) return;
    int2 oe = offse[i];
    int j = lane & 3;
    const float4* g4 = (const float4*)g;
    float4 a = make_float4(0.f, 0.f, 0.f, 0.f);
    for (int e = oe.x + (lane >> 2); e < oe.y; e += 16) {
        int s = ebuf2[e];
        float4 vv = g4[(size_t)s * 4 + j];
        a.x += vv.x;
        a.y += vv.y;
        a.z += vv.z;
        a.w += vv.w;
    }
#pragma unroll
    for (int mk = 4; mk <= 32; mk <<= 1) {
        a.x += __shfl_xor(a.x, mk);
        a.y += __shfl_xor(a.y, mk);
        a.z += __shfl_xor(a.z, mk);
        a.w += __shfl_xor(a.w, mk);
    }
    float dv = dinv[i];
    float4 self = g4[(size_t)i * 4 + j];
    float4 bb = ((const float4*)b1)[j];
    float4 o;
    o.x = fmaxf(dv * (a.x + self.x) + bb.x, 0.f);
    o.y = fmaxf(dv * (a.y + self.y) + bb.y, 0.f);
    o.z = fmaxf(dv * (a.z + self.z) + bb.z, 0.f);
    o.w = fmaxf(dv * (a.w + self.w) + bb.w, 0.f);
    // gemm2 partials: lane j covers k = 4j..4j+3
    float4 pv[4];
#pragma unroll
    for (int q = 0; q < 4; q++) {
        int n0 = 4 * q;
        pv[q].x = o.x * w2s[(4 * j + 0) * HID + n0 + 0] + o.y * w2s[(4 * j + 1) * HID + n0 + 0] +
                  o.z * w2s[(4 * j + 2) * HID + n0 + 0] + o.w * w2s[(4 * j + 3) * HID + n0 + 0];
        pv[q].y = o.x * w2s[(4 * j + 0) * HID + n0 + 1] + o.y * w2s[(4 * j + 1) * HID + n0 + 1] +
                  o.z * w2s[(4 * j + 2) * HID + n0 + 1] + o.w * w2s[(4 * j + 3) * HID + n0 + 1];
        pv[q].z = o.x * w2s[(4 * j + 0) * HID + n0 + 2] + o.y * w2s[(4 * j + 1) * HID + n0 + 2] +
                  o.z * w2s[(4 * j + 2) * HID + n0 + 2] + o.w * w2s[(4 * j + 3) * HID + n0 + 2];
        pv[q].w = o.x * w2s[(4 * j + 0) * HID + n0 + 3] + o.y * w2s[(4 * j + 1) * HID + n0 + 3] +
                  o.z * w2s[(4 * j + 2) * HID + n0 + 3] + o.w * w2s[(4 * j + 3) * HID + n0 + 3];
    }
#pragma unroll
    for (int mk = 1; mk <= 2; mk <<= 1) {
#pragma unroll
        for (int q = 0; q < 4; q++) {
            pv[q].x += __shfl_xor(pv[q].x, mk);
            pv[q].y += __shfl_xor(pv[q].y, mk);
            pv[q].z += __shfl_xor(pv[q].z, mk);
            pv[q].w += __shfl_xor(pv[q].w, mk);
        }
    }
    if (lane < 4) {
        float4 outv;
        outv.x = pv[j].x * dv;
        outv.y = pv[j].y * dv;
        outv.z = pv[j].z * dv;
        outv.w = pv[j].w * dv;
        ((float4*)g2)[(size_t)i * 4 + j] = outv;
    }
}

// ---------------- gather conv2 + fused node-dot: nd = (dot(h2,Wf_lo), dot(h2,Wf_hi)+bf) ----------------
__global__ __launch_bounds__(256) void k_gather2(const float* __restrict__ g2,
                                                 const int2* __restrict__ offse,
                                                 const int* __restrict__ ebuf2,
                                                 const float* __restrict__ dinv,
                                                 const float* __restrict__ b2,
                                                 const float* __restrict__ Wf,
                                                 const float* __restrict__ bf,
                                                 float2* __restrict__ nd, int N) {
    __shared__ float wfs[33];
    if (threadIdx.x < 33) wfs[threadIdx.x] = (threadIdx.x < 32) ? Wf[threadIdx.x] : bf[0];
    __syncthreads();
    int i = (blockIdx.x * 256 + threadIdx.x) >> 6;
    int lane = threadIdx.x & 63;
    if (i >= N) return;
    int2 oe = offse[i];
    int j = lane & 3;
    const float4* g4 = (const float4*)g2;
    float4 a = make_float4(0.f, 0.f, 0.f, 0.f);
    for (int e = oe.x + (lane >> 2); e < oe.y; e += 16) {
        int s = ebuf2[e];
        float4 vv = g4[(size_t)s * 4 + j];
        a.x += vv.x;
        a.y += vv.y;
        a.z += vv.z;
        a.w += vv.w;
    }
#pragma unroll
    for (int mk = 4; mk <= 32; mk <<= 1) {
        a.x += __shfl_xor(a.x, mk);
        a.y += __shfl_xor(a.y, mk);
        a.z += __shfl_xor(a.z, mk);
        a.w += __shfl_xor(a.w, mk);
    }
    float dv = dinv[i];
    float4 self = g4[(size_t)i * 4 + j];
    float4 bb = ((const float4*)b2)[j];
    float4 o;
    o.x = dv * (a.x + self.x) + bb.x;
    o.y = dv * (a.y + self.y) + bb.y;
    o.z = dv * (a.z + self.z) + bb.z;
    o.w = dv * (a.w + self.w) + bb.w;
    float ps = o.x * wfs[4 * j + 0] + o.y * wfs[4 * j + 1] + o.z * wfs[4 * j + 2] + o.w * wfs[4 * j + 3];
    float pd = o.x * wfs[16 + 4 * j + 0] + o.y * wfs[16 + 4 * j + 1] + o.z * wfs[16 + 4 * j + 2] +
               o.w * wfs[16 + 4 * j + 3];
    ps += __shfl_xor(ps, 1);
    ps += __shfl_xor(ps, 2);
    pd += __shfl_xor(pd, 1);
    pd += __shfl_xor(pd, 2);
    if (lane == 0) nd[i] = make_float2(ps, pd + wfs[32]);
}

// ---------------- edge scoring: 8 B random reads from L2-resident nd ----------------
__global__ __launch_bounds__(256) void k_edge2(const int* __restrict__ src,
                                               const int* __restrict__ dst,
                                               const float2* __restrict__ nd,
                                               float* __restrict__ pred, int E) {
    int e = blockIdx.x * 256 + threadIdx.x;
    if (e >= E) return;
    pred[e] = nd[src[e]].x + nd[dst[e]].y;
}

extern "C" void kernel_launch(void* const* d_in, const int* in_sizes, int n_in,
                              void* d_out, int out_size, void* d_ws, size_t ws_size,
                              hipStream_t stream) {
    const float* x  = (const float*)d_in[0];
    const int*   ei = (const int*)d_in[1];
    const float* W1 = (const float*)d_in[2];
    const float* b1 = (const float*)d_in[3];
    const float* W2 = (const float*)d_in[4];
    const float* b2 = (const float*)d_in[5];
    const float* Wf = (const float*)d_in[6];
    const float* bf = (const float*)d_in[7];
    float* pred = (float*)d_out;

    const int N = N_NODES, E = N_EDGES;
    const int* src = ei;
    const int* dst = ei + E;

    // workspace layout (bytes); g2 aliases ebuf (dead after k_sort2). Total ~38 MB.
    char* w = (char*)d_ws;
    int*      cursor = (int*)(w + 0x0);           // 25 KB (stride CPAD)
    float*    dinv   = (float*)(w + 0x10000);     // 400 KB
    int2*     offse  = (int2*)(w + 0x80000);      // 800 KB
    float2*   nd     = (float2*)(w + 0x150000);   // 800 KB
    unsigned* ebuf   = (unsigned*)(w + 0x220000); // 391*9216*4 = 14.42 MB
    float*    g2     = (float*)(w + 0x220000);    // 6.4 MB (aliases ebuf)
    int*      ebuf2  = (int*)(w + 0x1000000);     // 14.42 MB
    float*    g      = (float*)(w + 0x1E00000);   // 6.4 MB -> end 0x2440000

    const int B = 256;
    int gE   = (E + B - 1) / B;  // 12500
    int gN64 = (N * 64) / B;     // 25000 (wave per node)

    hipMemsetAsync(cursor, 0, NB * CPAD * sizeof(int), stream);
    k_part<<<NCHUNK, B, 0, stream>>>(src, dst, cursor, ebuf, E);
    k_sort2<<<2 * NB, B, 0, stream>>>(ebuf, cursor, x, W1, ebuf2, offse, dinv, g, N);
    k_gather1<<<gN64, B, 0, stream>>>(g, offse, ebuf2, dinv, b1, W2, g2, N);
    k_gather2<<<gN64, B, 0, stream>>>(g2, offse, ebuf2, dinv, b2, Wf, bf, nd, N);
    k_edge2<<<gE, B, 0, stream>>>(src, dst, nd, pred, E);
}

// Round 8
// 245.296 us; speedup vs baseline: 1.3212x; 1.3212x over previous
//
#include <hip/hip_runtime.h>
#include <hip/hip_fp16.h>

#define N_NODES 100000
#define N_EDGES 3200000
#define F_IN 128
#define HID 16

#define SHIFT 8
#define NPB 256                                 // nodes per bucket
#define NB 391                                  // ceil(N/256)
#define CHUNK 3072
#define NCHUNK ((N_EDGES + CHUNK - 1) / CHUNK)  // 1042
#define MAXBE 9216                              // region cap per bucket (mean 8192, +11 sigma)
#define HALF 4608                               // region cap per half-bucket (mean 4096, +8 sigma)
#define CPAD 16

__device__ __forceinline__ float2 h2f(unsigned u) {
    __half2 h;
    *reinterpret_cast<unsigned*>(&h) = u;
    return __half22float2(h);
}
__device__ __forceinline__ unsigned f2h(float a, float b) {
    __half2 h = __floats2half2_rn(a, b);
    return *reinterpret_cast<unsigned*>(&h);
}

// ---------------- partition into fixed bucket regions, LDS-staged coalesced writes ----------------
__global__ __launch_bounds__(256) void k_part(const int* __restrict__ src,
                                              const int* __restrict__ dst,
                                              int* __restrict__ cursor,
                                              unsigned* __restrict__ ebuf, int E) {
    __shared__ int lcnt[512];
    __shared__ int sc[512];
    __shared__ int lcur[512];
    __shared__ int dlt[512];
    __shared__ unsigned sbuf[CHUNK];         // 12 KB
    __shared__ unsigned short sbkt[CHUNK];   // 6 KB
    int t = threadIdx.x;
    lcnt[t] = 0;
    lcnt[t + 256] = 0;
    __syncthreads();
    int e0 = blockIdx.x * CHUNK;
    int ne = min(CHUNK, E - e0);
    for (int e = t; e < ne; e += 256) atomicAdd(&lcnt[dst[e0 + e] >> SHIFT], 1);
    __syncthreads();
    sc[t] = lcnt[t];
    sc[t + 256] = lcnt[t + 256];
    __syncthreads();
#pragma unroll
    for (int o = 1; o < 256; o <<= 1) {
        int xv = (t >= o) ? sc[t - o] : 0;
        int yv = (t >= o) ? sc[256 + t - o] : 0;
        __syncthreads();
        sc[t] += xv;
        sc[256 + t] += yv;
        __syncthreads();
    }
    int tot1 = sc[255];
    __syncthreads();
    sc[256 + t] += tot1;
    __syncthreads();
    {
        int b1 = t, b2 = t + 256;
        int c1 = lcnt[b1], c2 = lcnt[b2];
        int o1 = sc[b1] - c1, o2 = sc[b2] - c2;
        lcur[b1] = o1;
        lcur[b2] = o2;
        if (b1 < NB && c1) dlt[b1] = b1 * MAXBE + atomicAdd(&cursor[b1 * CPAD], c1) - o1;
        if (b2 < NB && c2) dlt[b2] = b2 * MAXBE + atomicAdd(&cursor[b2 * CPAD], c2) - o2;
    }
    __syncthreads();
    for (int e = t; e < ne; e += 256) {
        int d = dst[e0 + e];
        int b = d >> SHIFT;
        int p = atomicAdd(&lcur[b], 1);
        sbuf[p] = ((unsigned)src[e0 + e] << SHIFT) | (unsigned)(d & (NPB - 1));
        sbkt[p] = (unsigned short)b;
    }
    __syncthreads();
    for (int k = t; k < ne; k += 256) ebuf[k + dlt[sbkt[k]]] = sbuf[k];
}

// ---------------- half-bucket counting-sort -> exact CSR (+dinv) + fused GEMM1 (fp16 out) ----------------
__global__ __launch_bounds__(256) void k_sort2(const unsigned* __restrict__ ebuf,
                                               const int* __restrict__ cursor,
                                               const float* __restrict__ x,
                                               const float* __restrict__ W1,
                                               int* __restrict__ ebuf2,
                                               int2* __restrict__ offse,
                                               float* __restrict__ dinv,
                                               uint4* __restrict__ gt, int N) {
    __shared__ int hist[128];
    __shared__ int sc2[128];
    __shared__ int cur[128];
    __shared__ int dg[128];
    __shared__ int sbufS[HALF];       // 18 KB
    __shared__ float w1s[F_IN * HID]; // 8 KB
    int t = threadIdx.x;
    int b = blockIdx.x >> 1, h = blockIdx.x & 1;
    for (int idx = t; idx < F_IN * HID; idx += 256) w1s[idx] = W1[idx];
    if (t < 128) hist[t] = 0;
    __syncthreads();
    int cnt = cursor[b * CPAD];
    int base_r = b * MAXBE;
    for (int e = t; e < cnt; e += 256) {
        unsigned u = ebuf[base_r + e];
        unsigned dl = u & 255u;
        if ((int)(dl >> 7) == h) atomicAdd(&hist[dl & 127], 1);
    }
    __syncthreads();
    int v = (t < 128) ? hist[t] : 0;
    if (t < 128) sc2[t] = v;
    __syncthreads();
    for (int o = 1; o < 128; o <<= 1) {
        int xv = (t < 128 && t >= o) ? sc2[t - o] : 0;
        __syncthreads();
        if (t < 128) sc2[t] += xv;
        __syncthreads();
    }
    int base_w = (2 * b + h) * HALF;
    if (t < 128) {
        int ex = sc2[t] - v;
        cur[t] = ex;
        dg[t] = v;
        int i = b * NPB + h * 128 + t;
        if (i < N) {
            offse[i] = make_int2(base_w + ex, base_w + ex + v);
            dinv[i] = rsqrtf((float)(v + 1));  // +1 self-loop
        }
    }
    __syncthreads();
    for (int e = t; e < cnt; e += 256) {
        unsigned u = ebuf[base_r + e];
        unsigned dl = u & 255u;
        if ((int)(dl >> 7) == h) {
            int p = atomicAdd(&cur[dl & 127], 1);
            sbufS[p] = (int)(u >> SHIFT);
        }
    }
    __syncthreads();
    int m = sc2[127];
    for (int k = t; k < m; k += 256) ebuf2[base_w + k] = sbufS[k];  // coalesced
    // ---- fused GEMM1: g = (x @ W1) * dinv, fp16 storage (2 lanes/row) ----
    int r = t >> 1, hf = t & 1;
    int i = b * NPB + h * 128 + r;
    float acc[HID];
#pragma unroll
    for (int n = 0; n < HID; n++) acc[n] = 0.f;
    if (i < N) {
        const float4* xr = (const float4*)(x + (size_t)i * F_IN + hf * (F_IN / 2));
#pragma unroll 4
        for (int k4 = 0; k4 < F_IN / 8; k4++) {
            float4 xv = xr[k4];
            int k = hf * (F_IN / 2) + k4 * 4;
#pragma unroll
            for (int n = 0; n < HID; n++) {
                acc[n] += xv.x * w1s[(k + 0) * HID + n] + xv.y * w1s[(k + 1) * HID + n] +
                          xv.z * w1s[(k + 2) * HID + n] + xv.w * w1s[(k + 3) * HID + n];
            }
        }
    }
#pragma unroll
    for (int n = 0; n < HID; n++) acc[n] += __shfl_xor(acc[n], 1);
    if (hf == 0 && i < N) {
        float dv = rsqrtf((float)(dg[r] + 1));
        uint4 w0, w1;
        w0.x = f2h(acc[0] * dv, acc[1] * dv);
        w0.y = f2h(acc[2] * dv, acc[3] * dv);
        w0.z = f2h(acc[4] * dv, acc[5] * dv);
        w0.w = f2h(acc[6] * dv, acc[7] * dv);
        w1.x = f2h(acc[8] * dv, acc[9] * dv);
        w1.y = f2h(acc[10] * dv, acc[11] * dv);
        w1.z = f2h(acc[12] * dv, acc[13] * dv);
        w1.w = f2h(acc[14] * dv, acc[15] * dv);
        gt[2 * (size_t)i] = w0;
        gt[2 * (size_t)i + 1] = w1;
    }
}

// ---------------- gather conv1 (fp16 table): h1 = relu(dinv*(sum+self)+b1), fp16 out ----------------
// wave per node; 2 lanes/edge (32 edges in flight); fp32 accumulation.
__global__ __launch_bounds__(256) void k_gather1(const uint4* __restrict__ gt,
                                                 const int2* __restrict__ offse,
                                                 const int* __restrict__ ebuf2,
                                                 const float* __restrict__ dinv,
                                                 const float* __restrict__ b1,
                                                 uint4* __restrict__ ht, int N) {
    int i = (blockIdx.x * 256 + threadIdx.x) >> 6;
    int lane = threadIdx.x & 63;
    if (i >= N) return;
    int2 oe = offse[i];
    int j = lane & 1;
    float2 a0 = make_float2(0.f, 0.f), a1 = a0, a2 = a0, a3 = a0;
    for (int e = oe.x + (lane >> 1); e < oe.y; e += 32) {
        int s = ebuf2[e];
        uint4 v = gt[2 * (size_t)s + j];
        float2 f;
        f = h2f(v.x); a0.x += f.x; a0.y += f.y;
        f = h2f(v.y); a1.x += f.x; a1.y += f.y;
        f = h2f(v.z); a2.x += f.x; a2.y += f.y;
        f = h2f(v.w); a3.x += f.x; a3.y += f.y;
    }
#pragma unroll
    for (int mk = 2; mk <= 32; mk <<= 1) {
        a0.x += __shfl_xor(a0.x, mk); a0.y += __shfl_xor(a0.y, mk);
        a1.x += __shfl_xor(a1.x, mk); a1.y += __shfl_xor(a1.y, mk);
        a2.x += __shfl_xor(a2.x, mk); a2.y += __shfl_xor(a2.y, mk);
        a3.x += __shfl_xor(a3.x, mk); a3.y += __shfl_xor(a3.y, mk);
    }
    if (lane < 2) {
        uint4 sv = gt[2 * (size_t)i + j];
        float2 f;
        f = h2f(sv.x); a0.x += f.x; a0.y += f.y;
        f = h2f(sv.y); a1.x += f.x; a1.y += f.y;
        f = h2f(sv.z); a2.x += f.x; a2.y += f.y;
        f = h2f(sv.w); a3.x += f.x; a3.y += f.y;
        float dv = dinv[i];
        float4 bb0 = ((const float4*)b1)[2 * j];
        float4 bb1 = ((const float4*)b1)[2 * j + 1];
        float o0 = fmaxf(dv * a0.x + bb0.x, 0.f), o1 = fmaxf(dv * a0.y + bb0.y, 0.f);
        float o2 = fmaxf(dv * a1.x + bb0.z, 0.f), o3 = fmaxf(dv * a1.y + bb0.w, 0.f);
        float o4 = fmaxf(dv * a2.x + bb1.x, 0.f), o5 = fmaxf(dv * a2.y + bb1.y, 0.f);
        float o6 = fmaxf(dv * a3.x + bb1.z, 0.f), o7 = fmaxf(dv * a3.y + bb1.w, 0.f);
        uint4 w;
        w.x = f2h(o0, o1);
        w.y = f2h(o2, o3);
        w.z = f2h(o4, o5);
        w.w = f2h(o6, o7);
        ht[2 * (size_t)i + j] = w;
    }
}

// ---------------- GEMM2: g2 = (h1 @ W2) * dinv, fp16 in/out ----------------
__global__ __launch_bounds__(256) void k_gemm2(const uint4* __restrict__ ht,
                                               const float* __restrict__ W2,
                                               const float* __restrict__ dinv,
                                               uint4* __restrict__ g2t, int N) {
    __shared__ float w[HID * HID];
    w[threadIdx.x] = W2[threadIdx.x];
    __syncthreads();
    int i = blockIdx.x * 256 + threadIdx.x;
    if (i >= N) return;
    uint4 r0 = ht[2 * (size_t)i], r1 = ht[2 * (size_t)i + 1];
    float hv[HID];
    float2 f;
    f = h2f(r0.x); hv[0] = f.x; hv[1] = f.y;
    f = h2f(r0.y); hv[2] = f.x; hv[3] = f.y;
    f = h2f(r0.z); hv[4] = f.x; hv[5] = f.y;
    f = h2f(r0.w); hv[6] = f.x; hv[7] = f.y;
    f = h2f(r1.x); hv[8] = f.x; hv[9] = f.y;
    f = h2f(r1.y); hv[10] = f.x; hv[11] = f.y;
    f = h2f(r1.z); hv[12] = f.x; hv[13] = f.y;
    f = h2f(r1.w); hv[14] = f.x; hv[15] = f.y;
    float dv = dinv[i];
    float out[HID];
#pragma unroll
    for (int n = 0; n < HID; n++) out[n] = 0.f;
#pragma unroll
    for (int k = 0; k < HID; k++) {
#pragma unroll
        for (int n = 0; n < HID; n++) out[n] += hv[k] * w[k * HID + n];
    }
    uint4 w0, w1;
    w0.x = f2h(out[0] * dv, out[1] * dv);
    w0.y = f2h(out[2] * dv, out[3] * dv);
    w0.z = f2h(out[4] * dv, out[5] * dv);
    w0.w = f2h(out[6] * dv, out[7] * dv);
    w1.x = f2h(out[8] * dv, out[9] * dv);
    w1.y = f2h(out[10] * dv, out[11] * dv);
    w1.z = f2h(out[12] * dv, out[13] * dv);
    w1.w = f2h(out[14] * dv, out[15] * dv);
    g2t[2 * (size_t)i] = w0;
    g2t[2 * (size_t)i + 1] = w1;
}

// ---------------- gather conv2 (fp16 table) + fused node-dot -> nd ----------------
__global__ __launch_bounds__(256) void k_gather2(const uint4* __restrict__ g2t,
                                                 const int2* __restrict__ offse,
                                                 const int* __restrict__ ebuf2,
                                                 const float* __restrict__ dinv,
                                                 const float* __restrict__ b2,
                                                 const float* __restrict__ Wf,
                                                 const float* __restrict__ bf,
                                                 float2* __restrict__ nd, int N) {
    __shared__ float wfs[33];
    if (threadIdx.x < 33) wfs[threadIdx.x] = (threadIdx.x < 32) ? Wf[threadIdx.x] : bf[0];
    __syncthreads();
    int i = (blockIdx.x * 256 + threadIdx.x) >> 6;
    int lane = threadIdx.x & 63;
    if (i >= N) return;
    int2 oe = offse[i];
    int j = lane & 1;
    float2 a0 = make_float2(0.f, 0.f), a1 = a0, a2 = a0, a3 = a0;
    for (int e = oe.x + (lane >> 1); e < oe.y; e += 32) {
        int s = ebuf2[e];
        uint4 v = g2t[2 * (size_t)s + j];
        float2 f;
        f = h2f(v.x); a0.x += f.x; a0.y += f.y;
        f = h2f(v.y); a1.x += f.x; a1.y += f.y;
        f = h2f(v.z); a2.x += f.x; a2.y += f.y;
        f = h2f(v.w); a3.x += f.x; a3.y += f.y;
    }
#pragma unroll
    for (int mk = 2; mk <= 32; mk <<= 1) {
        a0.x += __shfl_xor(a0.x, mk); a0.y += __shfl_xor(a0.y, mk);
        a1.x += __shfl_xor(a1.x, mk); a1.y += __shfl_xor(a1.y, mk);
        a2.x += __shfl_xor(a2.x, mk); a2.y += __shfl_xor(a2.y, mk);
        a3.x += __shfl_xor(a3.x, mk); a3.y += __shfl_xor(a3.y, mk);
    }
    if (lane < 2) {
        uint4 sv = g2t[2 * (size_t)i + j];
        float2 f;
        f = h2f(sv.x); a0.x += f.x; a0.y += f.y;
        f = h2f(sv.y); a1.x += f.x; a1.y += f.y;
        f = h2f(sv.z); a2.x += f.x; a2.y += f.y;
        f = h2f(sv.w); a3.x += f.x; a3.y += f.y;
        float dv = dinv[i];
        float4 bb0 = ((const float4*)b2)[2 * j];
        float4 bb1 = ((const float4*)b2)[2 * j + 1];
        float o0 = dv * a0.x + bb0.x, o1 = dv * a0.y + bb0.y;
        float o2 = dv * a1.x + bb0.z, o3 = dv * a1.y + bb0.w;
        float o4 = dv * a2.x + bb1.x, o5 = dv * a2.y + bb1.y;
        float o6 = dv * a3.x + bb1.z, o7 = dv * a3.y + bb1.w;
        int k0 = 8 * j;
        float ps = o0 * wfs[k0 + 0] + o1 * wfs[k0 + 1] + o2 * wfs[k0 + 2] + o3 * wfs[k0 + 3] +
                   o4 * wfs[k0 + 4] + o5 * wfs[k0 + 5] + o6 * wfs[k0 + 6] + o7 * wfs[k0 + 7];
        float pd = o0 * wfs[16 + k0 + 0] + o1 * wfs[16 + k0 + 1] + o2 * wfs[16 + k0 + 2] +
                   o3 * wfs[16 + k0 + 3] + o4 * wfs[16 + k0 + 4] + o5 * wfs[16 + k0 + 5] +
                   o6 * wfs[16 + k0 + 6] + o7 * wfs[16 + k0 + 7];
        ps += __shfl_xor(ps, 1);
        pd += __shfl_xor(pd, 1);
        if (lane == 0) nd[i] = make_float2(ps, pd + wfs[32]);
    }
}

// ---------------- edge scoring: 8 B random reads from L2-resident nd ----------------
__global__ __launch_bounds__(256) void k_edge2(const int* __restrict__ src,
                                               const int* __restrict__ dst,
                                               const float2* __restrict__ nd,
                                               float* __restrict__ pred, int E) {
    int e = blockIdx.x * 256 + threadIdx.x;
    if (e >= E) return;
    pred[e] = nd[src[e]].x + nd[dst[e]].y;
}

extern "C" void kernel_launch(void* const* d_in, const int* in_sizes, int n_in,
                              void* d_out, int out_size, void* d_ws, size_t ws_size,
                              hipStream_t stream) {
    const float* x  = (const float*)d_in[0];
    const int*   ei = (const int*)d_in[1];
    const float* W1 = (const float*)d_in[2];
    const float* b1 = (const float*)d_in[3];
    const float* W2 = (const float*)d_in[4];
    const float* b2 = (const float*)d_in[5];
    const float* Wf = (const float*)d_in[6];
    const float* bf = (const float*)d_in[7];
    float* pred = (float*)d_out;

    const int N = N_NODES, E = N_EDGES;
    const int* src = ei;
    const int* dst = ei + E;

    // workspace layout (bytes); g2t aliases ebuf (dead after k_sort2). Total ~38 MB.
    char* w = (char*)d_ws;
    int*      cursor = (int*)(w + 0x0);           // 25 KB (stride CPAD)
    float*    dinv   = (float*)(w + 0x10000);     // 400 KB
    int2*     offse  = (int2*)(w + 0x80000);      // 800 KB
    float2*   nd     = (float2*)(w + 0x150000);   // 800 KB
    unsigned* ebuf   = (unsigned*)(w + 0x220000); // 391*9216*4 = 14.42 MB (dead after sort2)
    uint4*    g2t    = (uint4*)(w + 0x220000);    // 3.2 MB (aliases ebuf)
    int*      ebuf2  = (int*)(w + 0x1000000);     // 14.42 MB
    uint4*    gt     = (uint4*)(w + 0x1E00000);   // 3.2 MB (fp16 g table)
    uint4*    ht     = (uint4*)(w + 0x2140000);   // 3.2 MB (fp16 h1) -> end ~0x2450000

    const int B = 256;
    int gE   = (E + B - 1) / B;  // 12500
    int gN   = (N + B - 1) / B;  // 391
    int gN64 = (N * 64) / B;     // 25000 (wave per node)

    hipMemsetAsync(cursor, 0, NB * CPAD * sizeof(int), stream);
    k_part<<<NCHUNK, B, 0, stream>>>(src, dst, cursor, ebuf, E);
    k_sort2<<<2 * NB, B, 0, stream>>>(ebuf, cursor, x, W1, ebuf2, offse, dinv, gt, N);
    k_gather1<<<gN64, B, 0, stream>>>(gt, offse, ebuf2, dinv, b1, ht, N);
    k_gemm2<<<gN, B, 0, stream>>>(ht, W2, dinv, g2t, N);
    k_gather2<<<gN64, B, 0, stream>>>(g2t, offse, ebuf2, dinv, b2, Wf, bf, nd, N);
    k_edge2<<<gE, B, 0, stream>>>(src, dst, nd, pred, E);
}